// Round 3
// baseline (2390.565 us; speedup 1.0000x reference)
//
#include <hip/hip_runtime.h>
#include <math.h>

#define NN 50000
#define NE 800000
#define HID 128
#define NNH ((size_t)NN * HID)
#define NPAD 50176

typedef __attribute__((ext_vector_type(8))) short short8;
typedef __attribute__((ext_vector_type(4))) float f32x4;

__device__ __forceinline__ ushort f2bf(float f) {
  unsigned u = __float_as_uint(f);
  unsigned r = (u + 0x7fffu + ((u >> 16) & 1u)) >> 16;
  return (ushort)r;
}
__device__ __forceinline__ float silu_f(float x) { return x / (1.0f + __expf(-x)); }

// ---------------- utility kernels ----------------
__global__ __launch_bounds__(256) void zero4_kernel(float4* __restrict__ p, int n4)
{
  int i = blockIdx.x * 256 + threadIdx.x;
  if (i < n4) p[i] = make_float4(0.f, 0.f, 0.f, 0.f);
}
__global__ __launch_bounds__(256) void zero_i(int* __restrict__ p, int n)
{
  int i = blockIdx.x * 256 + threadIdx.x;
  if (i < n) p[i] = 0;
}

__global__ __launch_bounds__(256) void ln_kernel(const float* __restrict__ h,
    const float* __restrict__ g, const float* __restrict__ b,
    float* __restrict__ o, int n)
{
  int r = blockIdx.x * 4 + (threadIdx.x >> 6);
  int lane = threadIdx.x & 63;
  if (r >= n) return;
  const float* hr = h + (size_t)r * HID;
  float v0 = hr[lane], v1 = hr[lane + 64];
  float s1 = v0 + v1, s2 = v0 * v0 + v1 * v1;
  #pragma unroll
  for (int m = 1; m < 64; m <<= 1) {
    s1 += __shfl_xor(s1, m, 64);
    s2 += __shfl_xor(s2, m, 64);
  }
  float mu = s1 * (1.0f / 128.0f);
  float var = s2 * (1.0f / 128.0f) - mu * mu;
  float rs = rsqrtf(var + 1e-5f);
  float* orow = o + (size_t)r * HID;
  orow[lane]      = (v0 - mu) * rs * g[lane]      + b[lane];
  orow[lane + 64] = (v1 - mu) * rs * g[lane + 64] + b[lane + 64];
}

// ---------------- counting sort of edges by src ----------------
__global__ __launch_bounds__(256) void count_src(const int* __restrict__ src, int* __restrict__ cnt)
{
  int e = blockIdx.x * 256 + threadIdx.x;
  if (e < NE) atomicAdd(&cnt[src[e]], 1);
}

__global__ __launch_bounds__(1024) void scan_excl(const int* __restrict__ cnt, int* __restrict__ base, int n)
{
  __shared__ int ws[16];
  int t = threadIdx.x;
  const int per = (n + 1023) / 1024;
  int s0 = t * per;
  int sum = 0;
  for (int i = 0; i < per; ++i) { int idx = s0 + i; if (idx < n) sum += cnt[idx]; }
  int lane = t & 63, w = t >> 6;
  int v = sum;
  #pragma unroll
  for (int m = 1; m < 64; m <<= 1) { int o = __shfl_up(v, m, 64); if (lane >= m) v += o; }
  if (lane == 63) ws[w] = v;
  __syncthreads();
  if (t == 0) { int a = 0; for (int i = 0; i < 16; ++i) { int x = ws[i]; ws[i] = a; a += x; } }
  __syncthreads();
  int run = ws[w] + v - sum;   // exclusive prefix at s0
  for (int i = 0; i < per; ++i) {
    int idx = s0 + i;
    if (idx < n) { base[idx] = run; run += cnt[idx]; }
  }
}

__global__ __launch_bounds__(256) void place_edges(const int* __restrict__ src, const int* __restrict__ dst,
    const int* __restrict__ base, int* __restrict__ cur,
    int* __restrict__ src_s, int* __restrict__ dst_s, int* __restrict__ perm)
{
  int e = blockIdx.x * 256 + threadIdx.x;
  if (e >= NE) return;
  int s = src[e];
  int p = base[s] + atomicAdd(&cur[s], 1);
  src_s[p] = s; dst_s[p] = dst[e]; perm[p] = e;
}

__global__ __launch_bounds__(256) void permute_ea(const float4* __restrict__ ea,
    const int* __restrict__ perm, float4* __restrict__ ea_s)
{
  int i = blockIdx.x * 256 + threadIdx.x;
  if (i >= NE * 4) return;
  int e = i >> 2, q = i & 3;
  ea_s[i] = ea[(size_t)perm[e] * 4 + q];
}

// ---------------- weight conversion ----------------
__global__ __launch_bounds__(256) void cvt4(const float* __restrict__ s0, const float* __restrict__ s1,
    const float* __restrict__ s2, const float* __restrict__ s3, ushort* __restrict__ d)
{
  int i = blockIdx.x * 256 + threadIdx.x;
  if (i >= 65536) return;
  const float* s = (i < 16384) ? s0 : (i < 32768) ? s1 : (i < 49152) ? s2 : s3;
  d[i] = f2bf(s[i & 16383]);
}
// Wab: rows 0..127 = ew1[:,0:128], rows 128..255 = ew1[:,128:256]; per-layer dst stride 104448
__global__ __launch_bounds__(256) void cvt_wab(const float* __restrict__ s, ushort* __restrict__ d)
{
  int i = blockIdx.x * 256 + threadIdx.x;
  if (i >= 131072) return;
  int l = i >> 15, rem = i & 32767;
  int r = rem >> 7, c = rem & 127;
  int srow = r & 127, scol = ((r >> 7) << 7) + c;
  d[l * 104448 + r * 128 + c] = f2bf(s[(size_t)l * 34816 + srow * 272 + scol]);
}
__global__ __launch_bounds__(256) void cvt_w1c(const float* __restrict__ s, ushort* __restrict__ d)
{
  int i = blockIdx.x * 256 + threadIdx.x;
  if (i >= 16384) return;
  int l = i >> 12, rem = i & 4095;
  int r = rem >> 5, c = rem & 31;
  d[l * 104448 + r * 32 + c] = (c < 16) ? f2bf(s[(size_t)l * 34816 + r * 272 + 256 + c]) : (ushort)0;
}
__global__ __launch_bounds__(256) void cvt_std(const float* __restrict__ s, ushort* __restrict__ d,
    int rows, int cols, int lss)
{
  int i = blockIdx.x * 256 + threadIdx.x;
  int n = 4 * rows * cols;
  if (i >= n) return;
  int rc = rows * cols;
  int l = i / rc, rem = i - l * rc;
  d[l * 104448 + rem] = f2bf(s[(size_t)l * lss + rem]);
}

// ---------------- MFMA GEMM: C = [R +] act(ln?(A @ W^T + bias)) ----------------
template<int KT, bool DOBIAS, bool DOLN, bool DOSILU, bool DORES>
__global__ __launch_bounds__(256) void mgemm(
    const float* __restrict__ A0, const float* __restrict__ A1,
    const ushort* __restrict__ Wbf, const float* __restrict__ bias,
    const float* __restrict__ lng, const float* __restrict__ lnb,
    const float* __restrict__ R, float* __restrict__ C, int n)
{
  constexpr int LDA = (KT == 256) ? 264 : 136;
  __shared__ ushort Al[64][LDA];
  const int tid = threadIdx.x;
  const int n0 = blockIdx.x * 64;

  constexpr int SPR = KT / 4;
  #pragma unroll
  for (int i = 0; i < (64 * KT / 4) / 256; ++i) {
    int s = tid + i * 256;
    int row = s / SPR;
    int c4 = (s % SPR) * 4;
    int gr = n0 + row;
    float4 v = make_float4(0.f, 0.f, 0.f, 0.f);
    if (gr < n) {
      if (KT == 256)
        v = (c4 < 128) ? *(const float4*)(A0 + (size_t)gr * HID + c4)
                       : *(const float4*)(A1 + (size_t)gr * HID + (c4 - 128));
      else
        v = *(const float4*)(A0 + (size_t)gr * HID + c4);
    }
    uint2 p;
    p.x = (uint)f2bf(v.x) | ((uint)f2bf(v.y) << 16);
    p.y = (uint)f2bf(v.z) | ((uint)f2bf(v.w) << 16);
    *(uint2*)&Al[row][c4] = p;
  }
  __syncthreads();

  const int w = tid >> 6, l = tid & 63;
  const int lr = l & 15, lh = l >> 4;

  f32x4 zf = {0.f, 0.f, 0.f, 0.f};
  f32x4 acc[8];
  #pragma unroll
  for (int nt = 0; nt < 8; ++nt) acc[nt] = zf;

  #pragma unroll
  for (int q = 0; q < KT / 32; ++q) {
    short8 af = *(const short8*)&Al[w * 16 + lr][q * 32 + lh * 8];
    #pragma unroll
    for (int nt = 0; nt < 8; ++nt) {
      short8 bf = *(const short8*)(Wbf + (size_t)(nt * 16 + lr) * KT + q * 32 + lh * 8);
      acc[nt] = __builtin_amdgcn_mfma_f32_16x16x32_bf16(af, bf, acc[nt], 0, 0, 0);
    }
  }

  float vb[8], gv[8], bv[8];
  #pragma unroll
  for (int nt = 0; nt < 8; ++nt) {
    int col = nt * 16 + lr;
    vb[nt] = DOBIAS ? bias[col] : 0.f;
    if (DOLN) { gv[nt] = lng[col]; bv[nt] = lnb[col]; }
  }

  #pragma unroll
  for (int r = 0; r < 4; ++r) {
    float vals[8];
    #pragma unroll
    for (int nt = 0; nt < 8; ++nt) vals[nt] = acc[nt][r] + vb[nt];
    if (DOLN) {
      float s1 = 0.f, s2 = 0.f;
      #pragma unroll
      for (int nt = 0; nt < 8; ++nt) { s1 += vals[nt]; s2 += vals[nt] * vals[nt]; }
      #pragma unroll
      for (int m = 1; m < 16; m <<= 1) { s1 += __shfl_xor(s1, m, 64); s2 += __shfl_xor(s2, m, 64); }
      float mu = s1 * (1.0f / 128.0f);
      float var = s2 * (1.0f / 128.0f) - mu * mu;
      float rs = rsqrtf(var + 1e-5f);
      #pragma unroll
      for (int nt = 0; nt < 8; ++nt) vals[nt] = (vals[nt] - mu) * rs * gv[nt] + bv[nt];
    }
    if (DOSILU) {
      #pragma unroll
      for (int nt = 0; nt < 8; ++nt) vals[nt] = silu_f(vals[nt]);
    }
    int row = n0 + w * 16 + lh * 4 + r;
    if (row < n) {
      float* cr = C + (size_t)row * HID;
      #pragma unroll
      for (int nt = 0; nt < 8; ++nt) {
        int col = nt * 16 + lr;
        float o = vals[nt];
        if (DORES) o += R[(size_t)row * HID + col];
        cr[col] = o;
      }
    }
  }
}

// ---------------- dual-output GEMM: Pa = hn@Wa^T + b1, Pb = hn@Wb^T ----------------
__global__ __launch_bounds__(256) void pab_gemm(
    const float* __restrict__ A, const ushort* __restrict__ Wab,   // [256][128] bf16
    const float* __restrict__ eb1, float* __restrict__ Pa, float* __restrict__ Pb, int n)
{
  __shared__ ushort Al[64][136];
  const int tid = threadIdx.x;
  const int n0 = blockIdx.x * 64;

  #pragma unroll
  for (int i = 0; i < 8; ++i) {
    int s = tid + i * 256;
    int row = s >> 5;
    int c4 = (s & 31) * 4;
    int gr = n0 + row;
    float4 v = make_float4(0.f, 0.f, 0.f, 0.f);
    if (gr < n) v = *(const float4*)(A + (size_t)gr * HID + c4);
    uint2 p;
    p.x = (uint)f2bf(v.x) | ((uint)f2bf(v.y) << 16);
    p.y = (uint)f2bf(v.z) | ((uint)f2bf(v.w) << 16);
    *(uint2*)&Al[row][c4] = p;
  }
  __syncthreads();

  const int w = tid >> 6, l = tid & 63;
  const int lr = l & 15, lh = l >> 4;

  f32x4 zf = {0.f, 0.f, 0.f, 0.f};
  f32x4 acc[16];
  #pragma unroll
  for (int nt = 0; nt < 16; ++nt) acc[nt] = zf;

  #pragma unroll
  for (int q = 0; q < 4; ++q) {
    short8 af = *(const short8*)&Al[w * 16 + lr][q * 32 + lh * 8];
    #pragma unroll
    for (int nt = 0; nt < 16; ++nt) {
      short8 bf = *(const short8*)(Wab + (size_t)(nt * 16 + lr) * HID + q * 32 + lh * 8);
      acc[nt] = __builtin_amdgcn_mfma_f32_16x16x32_bf16(af, bf, acc[nt], 0, 0, 0);
    }
  }

  #pragma unroll
  for (int r = 0; r < 4; ++r) {
    int row = n0 + w * 16 + lh * 4 + r;
    if (row >= n) break;
    float* pa = Pa + (size_t)row * HID;
    float* pb = Pb + (size_t)row * HID;
    #pragma unroll
    for (int nt = 0; nt < 8; ++nt) {
      int col = nt * 16 + lr;
      pa[col] = acc[nt][r] + eb1[col];
      pb[col] = acc[nt + 8][r];
    }
  }
}

// ---------------- fused edge kernel over SORTED edges ----------------
__global__ __launch_bounds__(256) void edge_sorted(
    const float* __restrict__ Pa, const float* __restrict__ Pb,
    const float* __restrict__ ea_s,
    const int* __restrict__ src_s, const int* __restrict__ dst_s,
    const ushort* __restrict__ W1c,
    const float* __restrict__ elg, const float* __restrict__ elb,
    const ushort* __restrict__ W2bf,
    const float* __restrict__ b2,
    float* __restrict__ agg)
{
  __shared__ ushort Ts[4][16][136];
  const int tid = threadIdx.x;
  const int w = tid >> 6, l = tid & 63;
  const int lr = l & 15, lh = l >> 4;
  const int e0 = blockIdx.x * 64 + w * 16;

  short8 af = {0, 0, 0, 0, 0, 0, 0, 0};
  if (lh < 2) {
    const float* p = ea_s + (size_t)(e0 + lr) * 16 + lh * 8;
    float4 u = *(const float4*)p, v = *(const float4*)(p + 4);
    af[0] = (short)f2bf(u.x); af[1] = (short)f2bf(u.y);
    af[2] = (short)f2bf(u.z); af[3] = (short)f2bf(u.w);
    af[4] = (short)f2bf(v.x); af[5] = (short)f2bf(v.y);
    af[6] = (short)f2bf(v.z); af[7] = (short)f2bf(v.w);
  }

  f32x4 zf = {0.f, 0.f, 0.f, 0.f};
  f32x4 acc[8];
  #pragma unroll
  for (int nt = 0; nt < 8; ++nt) acc[nt] = zf;
  #pragma unroll
  for (int nt = 0; nt < 8; ++nt) {
    short8 bf = *(const short8*)(W1c + (nt * 16 + lr) * 32 + lh * 8);
    acc[nt] = __builtin_amdgcn_mfma_f32_16x16x32_bf16(af, bf, acc[nt], 0, 0, 0);
  }

  int sr[4], dr[4];
  #pragma unroll
  for (int r = 0; r < 4; ++r) {
    int e = e0 + lh * 4 + r;
    sr[r] = src_s[e]; dr[r] = dst_s[e];
  }
  // sorted => monotone within wave; endpoints equal => all 16 edges share src
  int first = __shfl(sr[0], 0, 64);
  int last  = __shfl(sr[3], 48, 64);
  bool uni = (first == last);

  if (uni) {
    #pragma unroll
    for (int nt = 0; nt < 8; ++nt) {
      int col = nt * 16 + lr;
      float pav = Pa[(size_t)first * HID + col];
      #pragma unroll
      for (int r = 0; r < 4; ++r)
        acc[nt][r] += pav + Pb[(size_t)dr[r] * HID + col];
    }
  } else {
    #pragma unroll
    for (int nt = 0; nt < 8; ++nt) {
      int col = nt * 16 + lr;
      #pragma unroll
      for (int r = 0; r < 4; ++r)
        acc[nt][r] += Pa[(size_t)sr[r] * HID + col] + Pb[(size_t)dr[r] * HID + col];
    }
  }

  float gv[8], bv[8];
  #pragma unroll
  for (int nt = 0; nt < 8; ++nt) { gv[nt] = elg[nt * 16 + lr]; bv[nt] = elb[nt * 16 + lr]; }

  #pragma unroll
  for (int r = 0; r < 4; ++r) {
    float vals[8];
    #pragma unroll
    for (int nt = 0; nt < 8; ++nt) vals[nt] = acc[nt][r];
    float s1 = 0.f, s2 = 0.f;
    #pragma unroll
    for (int nt = 0; nt < 8; ++nt) { s1 += vals[nt]; s2 += vals[nt] * vals[nt]; }
    #pragma unroll
    for (int m = 1; m < 16; m <<= 1) { s1 += __shfl_xor(s1, m, 64); s2 += __shfl_xor(s2, m, 64); }
    float mu = s1 * (1.0f / 128.0f);
    float var = s2 * (1.0f / 128.0f) - mu * mu;
    float rs = rsqrtf(var + 1e-5f);
    #pragma unroll
    for (int nt = 0; nt < 8; ++nt) {
      float t = silu_f((vals[nt] - mu) * rs * gv[nt] + bv[nt]);
      Ts[w][lh * 4 + r][nt * 16 + lr] = f2bf(t);
    }
  }

  f32x4 acc2[8];
  #pragma unroll
  for (int nt = 0; nt < 8; ++nt) acc2[nt] = zf;
  #pragma unroll
  for (int q = 0; q < 4; ++q) {
    short8 a2 = *(const short8*)&Ts[w][lr][q * 32 + lh * 8];
    #pragma unroll
    for (int nt = 0; nt < 8; ++nt) {
      short8 bf = *(const short8*)(W2bf + (size_t)(nt * 16 + lr) * HID + q * 32 + lh * 8);
      acc2[nt] = __builtin_amdgcn_mfma_f32_16x16x32_bf16(a2, bf, acc2[nt], 0, 0, 0);
    }
  }

  #pragma unroll
  for (int nt = 0; nt < 8; ++nt) {
    int col = nt * 16 + lr;
    float bb = b2[col];
    if (uni) {
      float s = acc2[nt][0] + acc2[nt][1] + acc2[nt][2] + acc2[nt][3];
      s += __shfl_xor(s, 16, 64);
      s += __shfl_xor(s, 32, 64);
      if (lh == 0)
        unsafeAtomicAdd(agg + (size_t)first * HID + col, s + 16.0f * bb);
    } else {
      float run = acc2[nt][0] + bb;
      #pragma unroll
      for (int r = 1; r < 4; ++r) {
        if (sr[r] == sr[r - 1]) run += acc2[nt][r] + bb;
        else {
          unsafeAtomicAdd(agg + (size_t)sr[r - 1] * HID + col, run);
          run = acc2[nt][r] + bb;
        }
      }
      unsafeAtomicAdd(agg + (size_t)sr[3] * HID + col, run);
    }
  }
}

extern "C" void kernel_launch(void* const* d_in, const int* in_sizes, int n_in,
                              void* d_out, int out_size, void* d_ws, size_t ws_size,
                              hipStream_t stream)
{
  const float* in_h  = (const float*)d_in[0];
  const int*   edges = (const int*)d_in[1];
  const float* ea    = (const float*)d_in[2];
  const float* ei_w1 = (const float*)d_in[3];
  const float* ei_b1 = (const float*)d_in[4];
  const float* ei_w2 = (const float*)d_in[5];
  const float* ei_b2 = (const float*)d_in[6];
  const float* ng    = (const float*)d_in[7];
  const float* nbp   = (const float*)d_in[8];
  const float* ew1   = (const float*)d_in[9];
  const float* eb1   = (const float*)d_in[10];
  const float* elg   = (const float*)d_in[11];
  const float* elb   = (const float*)d_in[12];
  const float* ew2   = (const float*)d_in[13];
  const float* eb2   = (const float*)d_in[14];
  const float* nw1   = (const float*)d_in[15];
  const float* nb1   = (const float*)d_in[16];
  const float* nlg   = (const float*)d_in[17];
  const float* nlb   = (const float*)d_in[18];
  const float* nw2   = (const float*)d_in[19];
  const float* nb2   = (const float*)d_in[20];
  const float* eo_w1 = (const float*)d_in[21];
  const float* eo_b1 = (const float*)d_in[22];
  const float* eo_w2 = (const float*)d_in[23];
  const float* eo_b2 = (const float*)d_in[24];

  float* wf    = (float*)d_ws;
  float* B_h   = wf;
  float* B_hn  = wf + NNH;
  float* B_agg = wf + 2 * NNH;
  float* B_tmp = wf + 3 * NNH;   // Pa / MLP intermediate
  float* B_pb  = wf + 4 * NNH;

  const size_t WOFF = 5 * NNH;          // bf16 weights (as float slots)
  ushort* wu = (ushort*)(wf + WOFF);
  // layout: ei1@0, ei2@16384, eo1@32768, eo2@49152; per-layer base 65536 + l*104448:
  //   Wab@0 [256][128] | W2@32768 | N1@49152 [128][256] | N2@81920 | W1c@98304 [128][32]
  const size_t SOFF = WOFF + 262144;
  int* src_s = (int*)(wf + SOFF);
  int* dst_s = src_s + NE;
  int* cnt   = dst_s + NE;
  int* cur   = cnt + NPAD;
  int* base  = cur + NPAD;
  float* ea_s = (float*)(base + NPAD);
  int* perm  = (int*)B_agg;             // alias: only used during setup

  const int NB  = (NN + 63) / 64;
  const int EB  = NE / 64;
  const int LNB = (NN + 3) / 4;
  const int ZB  = ((int)(NNH / 4) + 255) / 256;
  const int NEB = (NE + 255) / 256;

  const int* erow = edges;
  const int* ecol = edges + NE;

  // ---- counting sort by src (once; reused by all 4 layers) ----
  zero_i<<<(2 * NPAD + 255) / 256, 256, 0, stream>>>(cnt, 2 * NPAD);          // cnt + cur
  count_src<<<NEB, 256, 0, stream>>>(erow, cnt);
  scan_excl<<<1, 1024, 0, stream>>>(cnt, base, NN);
  place_edges<<<NEB, 256, 0, stream>>>(erow, ecol, base, cur, src_s, dst_s, perm);
  permute_ea<<<(NE * 4 + 255) / 256, 256, 0, stream>>>((const float4*)ea, perm, (float4*)ea_s);

  // ---- weight conversion to bf16 ----
  cvt4<<<256, 256, 0, stream>>>(ei_w1, ei_w2, eo_w1, eo_w2, wu);
  cvt_wab<<<512, 256, 0, stream>>>(ew1, wu + 65536);
  cvt_w1c<<<64, 256, 0, stream>>>(ew1, wu + 65536 + 98304);
  cvt_std<<<(4 * 16384 + 255) / 256, 256, 0, stream>>>(ew2, wu + 65536 + 32768, 128, 128, 16384);
  cvt_std<<<(4 * 32768 + 255) / 256, 256, 0, stream>>>(nw1, wu + 65536 + 49152, 128, 256, 32768);
  cvt_std<<<(4 * 16384 + 255) / 256, 256, 0, stream>>>(nw2, wu + 65536 + 81920, 128, 128, 16384);

  // ---- embedding_in ----
  mgemm<128, true, false, true,  false><<<NB, 256, 0, stream>>>(in_h, nullptr, wu, ei_b1, nullptr, nullptr, nullptr, B_tmp, NN);
  mgemm<128, true, false, false, false><<<NB, 256, 0, stream>>>(B_tmp, nullptr, wu + 16384, ei_b2, nullptr, nullptr, nullptr, B_h, NN);

  for (int lyr = 0; lyr < 4; ++lyr) {
    ushort* lb = wu + 65536 + lyr * 104448;
    ln_kernel<<<LNB, 256, 0, stream>>>(B_h, ng + 128 * lyr, nbp + 128 * lyr, B_hn, NN);
    pab_gemm<<<NB, 256, 0, stream>>>(B_hn, lb, eb1 + 128 * lyr, B_tmp, B_pb, NN);
    zero4_kernel<<<ZB, 256, 0, stream>>>((float4*)B_agg, (int)(NNH / 4));
    edge_sorted<<<EB, 256, 0, stream>>>(B_tmp, B_pb, ea_s, src_s, dst_s,
        lb + 98304, elg + 128 * lyr, elb + 128 * lyr, lb + 32768, eb2 + 128 * lyr, B_agg);
    mgemm<256, true, true,  true,  false><<<NB, 256, 0, stream>>>(B_hn, B_agg, lb + 49152, nb1 + 128 * lyr,
        nlg + 128 * lyr, nlb + 128 * lyr, nullptr, B_tmp, NN);
    mgemm<128, true, false, false, true ><<<NB, 256, 0, stream>>>(B_tmp, nullptr, lb + 81920, nb2 + 128 * lyr,
        nullptr, nullptr, B_hn, B_h, NN);
  }

  // ---- embedding_out ----
  mgemm<128, true, false, true,  false><<<NB, 256, 0, stream>>>(B_h, nullptr, wu + 32768, eo_b1, nullptr, nullptr, nullptr, B_tmp, NN);
  mgemm<128, true, false, false, false><<<NB, 256, 0, stream>>>(B_tmp, nullptr, wu + 49152, eo_b2, nullptr, nullptr, nullptr, (float*)d_out, NN);
}

// Round 4
// 1909.964 us; speedup vs baseline: 1.2516x; 1.2516x over previous
//
#include <hip/hip_runtime.h>
#include <math.h>

#define NN 50000
#define NE 800000
#define HID 128
#define NNH ((size_t)NN * HID)
#define NPAD 50176

typedef __attribute__((ext_vector_type(8))) short short8;
typedef __attribute__((ext_vector_type(4))) float f32x4;

__device__ __forceinline__ ushort f2bf(float f) {
  unsigned u = __float_as_uint(f);
  unsigned r = (u + 0x7fffu + ((u >> 16) & 1u)) >> 16;
  return (ushort)r;
}
__device__ __forceinline__ float bf2f(ushort h) {
  return __uint_as_float(((unsigned)h) << 16);
}
__device__ __forceinline__ float silu_f(float x) { return x / (1.0f + __expf(-x)); }

// ---------------- utility kernels ----------------
__global__ __launch_bounds__(256) void zero4_kernel(float4* __restrict__ p, int n4)
{
  int i = blockIdx.x * 256 + threadIdx.x;
  if (i < n4) p[i] = make_float4(0.f, 0.f, 0.f, 0.f);
}
__global__ __launch_bounds__(256) void zero_i(int* __restrict__ p, int n)
{
  int i = blockIdx.x * 256 + threadIdx.x;
  if (i < n) p[i] = 0;
}

__global__ __launch_bounds__(256) void ln_kernel(const float* __restrict__ h,
    const float* __restrict__ g, const float* __restrict__ b,
    float* __restrict__ o, int n)
{
  int r = blockIdx.x * 4 + (threadIdx.x >> 6);
  int lane = threadIdx.x & 63;
  if (r >= n) return;
  const float* hr = h + (size_t)r * HID;
  float v0 = hr[lane], v1 = hr[lane + 64];
  float s1 = v0 + v1, s2 = v0 * v0 + v1 * v1;
  #pragma unroll
  for (int m = 1; m < 64; m <<= 1) {
    s1 += __shfl_xor(s1, m, 64);
    s2 += __shfl_xor(s2, m, 64);
  }
  float mu = s1 * (1.0f / 128.0f);
  float var = s2 * (1.0f / 128.0f) - mu * mu;
  float rs = rsqrtf(var + 1e-5f);
  float* orow = o + (size_t)r * HID;
  orow[lane]      = (v0 - mu) * rs * g[lane]      + b[lane];
  orow[lane + 64] = (v1 - mu) * rs * g[lane + 64] + b[lane + 64];
}

// ---------------- counting sort of edges by src ----------------
__global__ __launch_bounds__(256) void count_src(const int* __restrict__ src, int* __restrict__ cnt)
{
  int e = blockIdx.x * 256 + threadIdx.x;
  if (e < NE) atomicAdd(&cnt[src[e]], 1);
}

__global__ __launch_bounds__(1024) void scan_excl(const int* __restrict__ cnt, int* __restrict__ base, int n)
{
  __shared__ int ws[16];
  int t = threadIdx.x;
  const int per = (n + 1023) / 1024;
  int s0 = t * per;
  int sum = 0;
  for (int i = 0; i < per; ++i) { int idx = s0 + i; if (idx < n) sum += cnt[idx]; }
  int lane = t & 63, w = t >> 6;
  int v = sum;
  #pragma unroll
  for (int m = 1; m < 64; m <<= 1) { int o = __shfl_up(v, m, 64); if (lane >= m) v += o; }
  if (lane == 63) ws[w] = v;
  __syncthreads();
  if (t == 0) { int a = 0; for (int i = 0; i < 16; ++i) { int x = ws[i]; ws[i] = a; a += x; } }
  __syncthreads();
  int run = ws[w] + v - sum;
  for (int i = 0; i < per; ++i) {
    int idx = s0 + i;
    if (idx < n) { base[idx] = run; run += cnt[idx]; }
  }
}

__global__ __launch_bounds__(256) void place_edges(const int* __restrict__ src, const int* __restrict__ dst,
    const int* __restrict__ base, int* __restrict__ cur,
    int* __restrict__ src_s, int* __restrict__ dst_s, int* __restrict__ perm)
{
  int e = blockIdx.x * 256 + threadIdx.x;
  if (e >= NE) return;
  int s = src[e];
  int p = base[s] + atomicAdd(&cur[s], 1);
  src_s[p] = s; dst_s[p] = dst[e]; perm[p] = e;
}

// permute edge_attr into sorted order AND convert to bf16 ([NE][16] ushort)
__global__ __launch_bounds__(256) void permute_ea_bf(const float4* __restrict__ ea,
    const int* __restrict__ perm, ushort* __restrict__ ea_s)
{
  int i = blockIdx.x * 256 + threadIdx.x;
  if (i >= NE * 4) return;
  int e = i >> 2, q = i & 3;
  float4 v = ea[(size_t)perm[e] * 4 + q];
  uint2 p;
  p.x = (uint)f2bf(v.x) | ((uint)f2bf(v.y) << 16);
  p.y = (uint)f2bf(v.z) | ((uint)f2bf(v.w) << 16);
  *(uint2*)&ea_s[(size_t)e * 16 + q * 4] = p;
}

// ---------------- weight conversion ----------------
__global__ __launch_bounds__(256) void cvt4(const float* __restrict__ s0, const float* __restrict__ s1,
    const float* __restrict__ s2, const float* __restrict__ s3, ushort* __restrict__ d)
{
  int i = blockIdx.x * 256 + threadIdx.x;
  if (i >= 65536) return;
  const float* s = (i < 16384) ? s0 : (i < 32768) ? s1 : (i < 49152) ? s2 : s3;
  d[i] = f2bf(s[i & 16383]);
}
__global__ __launch_bounds__(256) void cvt_wab(const float* __restrict__ s, ushort* __restrict__ d)
{
  int i = blockIdx.x * 256 + threadIdx.x;
  if (i >= 131072) return;
  int l = i >> 15, rem = i & 32767;
  int r = rem >> 7, c = rem & 127;
  int srow = r & 127, scol = ((r >> 7) << 7) + c;
  d[l * 104448 + r * 128 + c] = f2bf(s[(size_t)l * 34816 + srow * 272 + scol]);
}
__global__ __launch_bounds__(256) void cvt_w1c(const float* __restrict__ s, ushort* __restrict__ d)
{
  int i = blockIdx.x * 256 + threadIdx.x;
  if (i >= 16384) return;
  int l = i >> 12, rem = i & 4095;
  int r = rem >> 5, c = rem & 31;
  d[l * 104448 + r * 32 + c] = (c < 16) ? f2bf(s[(size_t)l * 34816 + r * 272 + 256 + c]) : (ushort)0;
}
__global__ __launch_bounds__(256) void cvt_std(const float* __restrict__ s, ushort* __restrict__ d,
    int rows, int cols, int lss)
{
  int i = blockIdx.x * 256 + threadIdx.x;
  int n = 4 * rows * cols;
  if (i >= n) return;
  int rc = rows * cols;
  int l = i / rc, rem = i - l * rc;
  d[l * 104448 + rem] = f2bf(s[(size_t)l * lss + rem]);
}

// ---------------- MFMA GEMM: C = [R +] act(ln?(A @ W^T + bias)) ----------------
template<int KT, bool DOBIAS, bool DOLN, bool DOSILU, bool DORES>
__global__ __launch_bounds__(256) void mgemm(
    const float* __restrict__ A0, const float* __restrict__ A1,
    const ushort* __restrict__ Wbf, const float* __restrict__ bias,
    const float* __restrict__ lng, const float* __restrict__ lnb,
    const float* __restrict__ R, float* __restrict__ C, int n)
{
  constexpr int LDA = (KT == 256) ? 264 : 136;
  __shared__ ushort Al[64][LDA];
  const int tid = threadIdx.x;
  const int n0 = blockIdx.x * 64;

  constexpr int SPR = KT / 4;
  #pragma unroll
  for (int i = 0; i < (64 * KT / 4) / 256; ++i) {
    int s = tid + i * 256;
    int row = s / SPR;
    int c4 = (s % SPR) * 4;
    int gr = n0 + row;
    float4 v = make_float4(0.f, 0.f, 0.f, 0.f);
    if (gr < n) {
      if (KT == 256)
        v = (c4 < 128) ? *(const float4*)(A0 + (size_t)gr * HID + c4)
                       : *(const float4*)(A1 + (size_t)gr * HID + (c4 - 128));
      else
        v = *(const float4*)(A0 + (size_t)gr * HID + c4);
    }
    uint2 p;
    p.x = (uint)f2bf(v.x) | ((uint)f2bf(v.y) << 16);
    p.y = (uint)f2bf(v.z) | ((uint)f2bf(v.w) << 16);
    *(uint2*)&Al[row][c4] = p;
  }
  __syncthreads();

  const int w = tid >> 6, l = tid & 63;
  const int lr = l & 15, lh = l >> 4;

  f32x4 zf = {0.f, 0.f, 0.f, 0.f};
  f32x4 acc[8];
  #pragma unroll
  for (int nt = 0; nt < 8; ++nt) acc[nt] = zf;

  #pragma unroll
  for (int q = 0; q < KT / 32; ++q) {
    short8 af = *(const short8*)&Al[w * 16 + lr][q * 32 + lh * 8];
    #pragma unroll
    for (int nt = 0; nt < 8; ++nt) {
      short8 bf = *(const short8*)(Wbf + (size_t)(nt * 16 + lr) * KT + q * 32 + lh * 8);
      acc[nt] = __builtin_amdgcn_mfma_f32_16x16x32_bf16(af, bf, acc[nt], 0, 0, 0);
    }
  }

  float vb[8], gv[8], bv[8];
  #pragma unroll
  for (int nt = 0; nt < 8; ++nt) {
    int col = nt * 16 + lr;
    vb[nt] = DOBIAS ? bias[col] : 0.f;
    if (DOLN) { gv[nt] = lng[col]; bv[nt] = lnb[col]; }
  }

  #pragma unroll
  for (int r = 0; r < 4; ++r) {
    float vals[8];
    #pragma unroll
    for (int nt = 0; nt < 8; ++nt) vals[nt] = acc[nt][r] + vb[nt];
    if (DOLN) {
      float s1 = 0.f, s2 = 0.f;
      #pragma unroll
      for (int nt = 0; nt < 8; ++nt) { s1 += vals[nt]; s2 += vals[nt] * vals[nt]; }
      #pragma unroll
      for (int m = 1; m < 16; m <<= 1) { s1 += __shfl_xor(s1, m, 64); s2 += __shfl_xor(s2, m, 64); }
      float mu = s1 * (1.0f / 128.0f);
      float var = s2 * (1.0f / 128.0f) - mu * mu;
      float rs = rsqrtf(var + 1e-5f);
      #pragma unroll
      for (int nt = 0; nt < 8; ++nt) vals[nt] = (vals[nt] - mu) * rs * gv[nt] + bv[nt];
    }
    if (DOSILU) {
      #pragma unroll
      for (int nt = 0; nt < 8; ++nt) vals[nt] = silu_f(vals[nt]);
    }
    int row = n0 + w * 16 + lh * 4 + r;
    if (row < n) {
      float* cr = C + (size_t)row * HID;
      #pragma unroll
      for (int nt = 0; nt < 8; ++nt) {
        int col = nt * 16 + lr;
        float o = vals[nt];
        if (DORES) o += R[(size_t)row * HID + col];
        cr[col] = o;
      }
    }
  }
}

// ---------------- dual-output GEMM: Pa = hn@Wa^T + b1, Pb = hn@Wb^T ----------------
__global__ __launch_bounds__(256) void pab_gemm(
    const float* __restrict__ A, const ushort* __restrict__ Wab,
    const float* __restrict__ eb1, float* __restrict__ Pa, float* __restrict__ Pb, int n)
{
  __shared__ ushort Al[64][136];
  const int tid = threadIdx.x;
  const int n0 = blockIdx.x * 64;

  #pragma unroll
  for (int i = 0; i < 8; ++i) {
    int s = tid + i * 256;
    int row = s >> 5;
    int c4 = (s & 31) * 4;
    int gr = n0 + row;
    float4 v = make_float4(0.f, 0.f, 0.f, 0.f);
    if (gr < n) v = *(const float4*)(A + (size_t)gr * HID + c4);
    uint2 p;
    p.x = (uint)f2bf(v.x) | ((uint)f2bf(v.y) << 16);
    p.y = (uint)f2bf(v.z) | ((uint)f2bf(v.w) << 16);
    *(uint2*)&Al[row][c4] = p;
  }
  __syncthreads();

  const int w = tid >> 6, l = tid & 63;
  const int lr = l & 15, lh = l >> 4;

  f32x4 zf = {0.f, 0.f, 0.f, 0.f};
  f32x4 acc[16];
  #pragma unroll
  for (int nt = 0; nt < 16; ++nt) acc[nt] = zf;

  #pragma unroll
  for (int q = 0; q < 4; ++q) {
    short8 af = *(const short8*)&Al[w * 16 + lr][q * 32 + lh * 8];
    #pragma unroll
    for (int nt = 0; nt < 16; ++nt) {
      short8 bf = *(const short8*)(Wab + (size_t)(nt * 16 + lr) * HID + q * 32 + lh * 8);
      acc[nt] = __builtin_amdgcn_mfma_f32_16x16x32_bf16(af, bf, acc[nt], 0, 0, 0);
    }
  }

  #pragma unroll
  for (int r = 0; r < 4; ++r) {
    int row = n0 + w * 16 + lh * 4 + r;
    if (row >= n) break;
    float* pa = Pa + (size_t)row * HID;
    float* pb = Pb + (size_t)row * HID;
    #pragma unroll
    for (int nt = 0; nt < 8; ++nt) {
      int col = nt * 16 + lr;
      pa[col] = acc[nt][r] + eb1[col];
      pb[col] = acc[nt + 8][r];
    }
  }
}

// ---------------- edge kernel: T_e = SiLU(LN(Pa[src]+Pb[dst]+ea@W1c^T)); S[src] += T_e ----------------
__global__ __launch_bounds__(256) void edge_s(
    const float* __restrict__ Pa, const float* __restrict__ Pb,
    const ushort* __restrict__ ea_bf,
    const int* __restrict__ src_s, const int* __restrict__ dst_s,
    const ushort* __restrict__ W1c,
    const float* __restrict__ elg, const float* __restrict__ elb,
    float* __restrict__ S)
{
  const int tid = threadIdx.x;
  const int w = tid >> 6, l = tid & 63;
  const int lr = l & 15, lh = l >> 4;
  const int e0 = blockIdx.x * 64 + w * 16;

  short8 af = {0, 0, 0, 0, 0, 0, 0, 0};
  if (lh < 2) af = *(const short8*)(ea_bf + (size_t)(e0 + lr) * 16 + lh * 8);

  f32x4 zf = {0.f, 0.f, 0.f, 0.f};
  f32x4 acc[8];
  #pragma unroll
  for (int nt = 0; nt < 8; ++nt) acc[nt] = zf;
  #pragma unroll
  for (int nt = 0; nt < 8; ++nt) {
    short8 bf = *(const short8*)(W1c + (nt * 16 + lr) * 32 + lh * 8);
    acc[nt] = __builtin_amdgcn_mfma_f32_16x16x32_bf16(af, bf, acc[nt], 0, 0, 0);
  }

  int sr[4], dr[4];
  #pragma unroll
  for (int r = 0; r < 4; ++r) {
    int e = e0 + lh * 4 + r;
    sr[r] = src_s[e]; dr[r] = dst_s[e];
  }
  int first = __builtin_amdgcn_readfirstlane(sr[0]);
  int last  = __shfl(sr[3], 48, 64);
  bool uni = (first == last);

  if (uni) {
    #pragma unroll
    for (int nt = 0; nt < 8; ++nt) {
      int col = nt * 16 + lr;
      float pav = Pa[(size_t)first * HID + col];
      #pragma unroll
      for (int r = 0; r < 4; ++r)
        acc[nt][r] += pav + Pb[(size_t)dr[r] * HID + col];
    }
  } else {
    #pragma unroll
    for (int nt = 0; nt < 8; ++nt) {
      int col = nt * 16 + lr;
      #pragma unroll
      for (int r = 0; r < 4; ++r)
        acc[nt][r] += Pa[(size_t)sr[r] * HID + col] + Pb[(size_t)dr[r] * HID + col];
    }
  }

  float gv[8], bv[8];
  #pragma unroll
  for (int nt = 0; nt < 8; ++nt) { gv[nt] = elg[nt * 16 + lr]; bv[nt] = elb[nt * 16 + lr]; }

  #pragma unroll
  for (int r = 0; r < 4; ++r) {
    float s1 = 0.f, s2 = 0.f;
    #pragma unroll
    for (int nt = 0; nt < 8; ++nt) { s1 += acc[nt][r]; s2 += acc[nt][r] * acc[nt][r]; }
    #pragma unroll
    for (int m = 1; m < 16; m <<= 1) { s1 += __shfl_xor(s1, m, 64); s2 += __shfl_xor(s2, m, 64); }
    float mu = s1 * (1.0f / 128.0f);
    float var = s2 * (1.0f / 128.0f) - mu * mu;
    float rs = rsqrtf(var + 1e-5f);
    #pragma unroll
    for (int nt = 0; nt < 8; ++nt)
      acc[nt][r] = silu_f((acc[nt][r] - mu) * rs * gv[nt] + bv[nt]);
  }

  #pragma unroll
  for (int nt = 0; nt < 8; ++nt) {
    int col = nt * 16 + lr;
    if (uni) {
      float s = acc[nt][0] + acc[nt][1] + acc[nt][2] + acc[nt][3];
      s += __shfl_xor(s, 16, 64);
      s += __shfl_xor(s, 32, 64);
      if (lh == 0)
        unsafeAtomicAdd(S + (size_t)first * HID + col, s);
    } else {
      float run = acc[nt][0];
      #pragma unroll
      for (int r = 1; r < 4; ++r) {
        if (sr[r] == sr[r - 1]) run += acc[nt][r];
        else {
          unsafeAtomicAdd(S + (size_t)sr[r - 1] * HID + col, run);
          run = acc[nt][r];
        }
      }
      unsafeAtomicAdd(S + (size_t)sr[3] * HID + col, run);
    }
  }
}

// ---------------- agg = (S_hi + S_lo) @ W2^T + deg*b2 (hi/lo bf16 split) ----------------
__global__ __launch_bounds__(256) void agg_gemm(
    const float* __restrict__ S, const ushort* __restrict__ W2bf,
    const float* __restrict__ b2, const int* __restrict__ deg,
    float* __restrict__ agg, int n)
{
  __shared__ ushort Ah[64][136];
  __shared__ ushort Alo[64][136];
  const int tid = threadIdx.x;
  const int n0 = blockIdx.x * 64;

  #pragma unroll
  for (int i = 0; i < 8; ++i) {
    int s = tid + i * 256;
    int row = s >> 5;
    int c4 = (s & 31) * 4;
    int gr = n0 + row;
    float4 v = make_float4(0.f, 0.f, 0.f, 0.f);
    if (gr < n) v = *(const float4*)(S + (size_t)gr * HID + c4);
    ushort hx = f2bf(v.x), hy = f2bf(v.y), hz = f2bf(v.z), hw = f2bf(v.w);
    uint2 ph, pl;
    ph.x = (uint)hx | ((uint)hy << 16);
    ph.y = (uint)hz | ((uint)hw << 16);
    pl.x = (uint)f2bf(v.x - bf2f(hx)) | ((uint)f2bf(v.y - bf2f(hy)) << 16);
    pl.y = (uint)f2bf(v.z - bf2f(hz)) | ((uint)f2bf(v.w - bf2f(hw)) << 16);
    *(uint2*)&Ah[row][c4]  = ph;
    *(uint2*)&Alo[row][c4] = pl;
  }
  __syncthreads();

  const int w = tid >> 6, l = tid & 63;
  const int lr = l & 15, lh = l >> 4;

  f32x4 zf = {0.f, 0.f, 0.f, 0.f};
  f32x4 acc[8];
  #pragma unroll
  for (int nt = 0; nt < 8; ++nt) acc[nt] = zf;

  #pragma unroll
  for (int q = 0; q < 4; ++q) {
    short8 ah = *(const short8*)&Ah[w * 16 + lr][q * 32 + lh * 8];
    short8 al = *(const short8*)&Alo[w * 16 + lr][q * 32 + lh * 8];
    #pragma unroll
    for (int nt = 0; nt < 8; ++nt) {
      short8 bf = *(const short8*)(W2bf + (size_t)(nt * 16 + lr) * HID + q * 32 + lh * 8);
      acc[nt] = __builtin_amdgcn_mfma_f32_16x16x32_bf16(ah, bf, acc[nt], 0, 0, 0);
      acc[nt] = __builtin_amdgcn_mfma_f32_16x16x32_bf16(al, bf, acc[nt], 0, 0, 0);
    }
  }

  #pragma unroll
  for (int r = 0; r < 4; ++r) {
    int row = n0 + w * 16 + lh * 4 + r;
    if (row >= n) break;
    float degf = (float)deg[row];
    float* ar = agg + (size_t)row * HID;
    #pragma unroll
    for (int nt = 0; nt < 8; ++nt) {
      int col = nt * 16 + lr;
      ar[col] = acc[nt][r] + degf * b2[col];
    }
  }
}

extern "C" void kernel_launch(void* const* d_in, const int* in_sizes, int n_in,
                              void* d_out, int out_size, void* d_ws, size_t ws_size,
                              hipStream_t stream)
{
  const float* in_h  = (const float*)d_in[0];
  const int*   edges = (const int*)d_in[1];
  const float* ea    = (const float*)d_in[2];
  const float* ei_w1 = (const float*)d_in[3];
  const float* ei_b1 = (const float*)d_in[4];
  const float* ei_w2 = (const float*)d_in[5];
  const float* ei_b2 = (const float*)d_in[6];
  const float* ng    = (const float*)d_in[7];
  const float* nbp   = (const float*)d_in[8];
  const float* ew1   = (const float*)d_in[9];
  const float* eb1   = (const float*)d_in[10];
  const float* elg   = (const float*)d_in[11];
  const float* elb   = (const float*)d_in[12];
  const float* ew2   = (const float*)d_in[13];
  const float* eb2   = (const float*)d_in[14];
  const float* nw1   = (const float*)d_in[15];
  const float* nb1   = (const float*)d_in[16];
  const float* nlg   = (const float*)d_in[17];
  const float* nlb   = (const float*)d_in[18];
  const float* nw2   = (const float*)d_in[19];
  const float* nb2   = (const float*)d_in[20];
  const float* eo_w1 = (const float*)d_in[21];
  const float* eo_b1 = (const float*)d_in[22];
  const float* eo_w2 = (const float*)d_in[23];
  const float* eo_b2 = (const float*)d_in[24];

  float* wf    = (float*)d_ws;
  float* B_h   = wf;
  float* B_hn  = wf + NNH;
  float* B_S   = wf + 2 * NNH;   // S (edge-sum); perm alias during setup
  float* B_tmp = wf + 3 * NNH;   // Pa / MLP intermediate
  float* B_pb  = wf + 4 * NNH;   // Pb during edge phase; agg afterwards

  const size_t WOFF = 5 * NNH;
  ushort* wu = (ushort*)(wf + WOFF);
  // ei1@0, ei2@16384, eo1@32768, eo2@49152; per-layer base 65536 + l*104448:
  //   Wab@0 [256][128] | W2@32768 | N1@49152 [128][256] | N2@81920 | W1c@98304 [128][32]
  const size_t SOFF = WOFF + 262144;
  int* src_s = (int*)(wf + SOFF);
  int* dst_s = src_s + NE;
  int* cnt   = dst_s + NE;       // = deg
  int* cur   = cnt + NPAD;
  int* base  = cur + NPAD;
  ushort* ea_s = (ushort*)(base + NPAD);
  int* perm  = (int*)B_S;

  const int NB  = (NN + 63) / 64;
  const int EB  = NE / 64;
  const int LNB = (NN + 3) / 4;
  const int ZB  = ((int)(NNH / 4) + 255) / 256;
  const int NEB = (NE + 255) / 256;

  const int* erow = edges;
  const int* ecol = edges + NE;

  // ---- counting sort by src (once) ----
  zero_i<<<(2 * NPAD + 255) / 256, 256, 0, stream>>>(cnt, 2 * NPAD);
  count_src<<<NEB, 256, 0, stream>>>(erow, cnt);
  scan_excl<<<1, 1024, 0, stream>>>(cnt, base, NN);
  place_edges<<<NEB, 256, 0, stream>>>(erow, ecol, base, cur, src_s, dst_s, perm);
  permute_ea_bf<<<(NE * 4 + 255) / 256, 256, 0, stream>>>((const float4*)ea, perm, ea_s);

  // ---- weight conversion to bf16 ----
  cvt4<<<256, 256, 0, stream>>>(ei_w1, ei_w2, eo_w1, eo_w2, wu);
  cvt_wab<<<512, 256, 0, stream>>>(ew1, wu + 65536);
  cvt_w1c<<<64, 256, 0, stream>>>(ew1, wu + 65536 + 98304);
  cvt_std<<<(4 * 16384 + 255) / 256, 256, 0, stream>>>(ew2, wu + 65536 + 32768, 128, 128, 16384);
  cvt_std<<<(4 * 32768 + 255) / 256, 256, 0, stream>>>(nw1, wu + 65536 + 49152, 128, 256, 32768);
  cvt_std<<<(4 * 16384 + 255) / 256, 256, 0, stream>>>(nw2, wu + 65536 + 81920, 128, 128, 16384);

  // ---- embedding_in ----
  mgemm<128, true, false, true,  false><<<NB, 256, 0, stream>>>(in_h, nullptr, wu, ei_b1, nullptr, nullptr, nullptr, B_tmp, NN);
  mgemm<128, true, false, false, false><<<NB, 256, 0, stream>>>(B_tmp, nullptr, wu + 16384, ei_b2, nullptr, nullptr, nullptr, B_h, NN);

  for (int lyr = 0; lyr < 4; ++lyr) {
    ushort* lb = wu + 65536 + lyr * 104448;
    ln_kernel<<<LNB, 256, 0, stream>>>(B_h, ng + 128 * lyr, nbp + 128 * lyr, B_hn, NN);
    pab_gemm<<<NB, 256, 0, stream>>>(B_hn, lb, eb1 + 128 * lyr, B_tmp, B_pb, NN);
    zero4_kernel<<<ZB, 256, 0, stream>>>((float4*)B_S, (int)(NNH / 4));
    edge_s<<<EB, 256, 0, stream>>>(B_tmp, B_pb, ea_s, src_s, dst_s,
        lb + 98304, elg + 128 * lyr, elb + 128 * lyr, B_S);
    agg_gemm<<<NB, 256, 0, stream>>>(B_S, lb + 32768, eb2 + 128 * lyr, cnt, B_pb, NN);
    mgemm<256, true, true,  true,  false><<<NB, 256, 0, stream>>>(B_hn, B_pb, lb + 49152, nb1 + 128 * lyr,
        nlg + 128 * lyr, nlb + 128 * lyr, nullptr, B_tmp, NN);
    mgemm<128, true, false, false, true ><<<NB, 256, 0, stream>>>(B_tmp, nullptr, lb + 81920, nb2 + 128 * lyr,
        nullptr, nullptr, B_hn, B_h, NN);
  }

  // ---- embedding_out ----
  mgemm<128, true, false, true,  false><<<NB, 256, 0, stream>>>(B_h, nullptr, wu + 32768, eo_b1, nullptr, nullptr, nullptr, B_tmp, NN);
  mgemm<128, true, false, false, false><<<NB, 256, 0, stream>>>(B_tmp, nullptr, wu + 49152, eo_b2, nullptr, nullptr, nullptr, (float*)d_out, NN);
}